// Round 3
// baseline (1460.740 us; speedup 1.0000x reference)
//
#include <hip/hip_runtime.h>
#include <math.h>

// Problem constants (match reference)
#define NB   64     // num_groups (B)
#define NG   32     // group_size (G)
#define ND   2000   // output dim D
#define NM   16     // m_samples
#define NE   16     // noise dim
#define NDIN 256
#define NK   272    // DIN + E
#define NDC  500    // d-chunk per k4 block (4-way split)

__device__ __forceinline__ float clampf(float v, float lo, float hi) {
    return fminf(fmaxf(v, lo), hi);
}

__device__ __forceinline__ float softplusf(float v) {
    return (v > 20.f) ? v : log1pf(expf(v));
}

// Fully-packed butterfly: reduce v[0..31] (per-g partials) across 64 lanes in
// 32 shuffles (vs 63 for the half-packed version).  On exit the wave total for
// g = (lane>>1)&31 is returned (duplicated on lane pairs {2g, 2g+1}).
__device__ __forceinline__ float wave_sum32(float v[NG], int lane) {
    {   const bool hi = (lane & 32) != 0;
        #pragma unroll
        for (int k = 0; k < 16; ++k) {
            float s = hi ? v[k] : v[k + 16];
            float r = __shfl_xor(s, 32);
            v[k] = (hi ? v[k + 16] : v[k]) + r;
        }
    }
    {   const bool hi = (lane & 16) != 0;
        #pragma unroll
        for (int k = 0; k < 8; ++k) {
            float s = hi ? v[k] : v[k + 8];
            float r = __shfl_xor(s, 16);
            v[k] = (hi ? v[k + 8] : v[k]) + r;
        }
    }
    {   const bool hi = (lane & 8) != 0;
        #pragma unroll
        for (int k = 0; k < 4; ++k) {
            float s = hi ? v[k] : v[k + 4];
            float r = __shfl_xor(s, 8);
            v[k] = (hi ? v[k + 4] : v[k]) + r;
        }
    }
    {   const bool hi = (lane & 4) != 0;
        #pragma unroll
        for (int k = 0; k < 2; ++k) {
            float s = hi ? v[k] : v[k + 2];
            float r = __shfl_xor(s, 4);
            v[k] = (hi ? v[k + 2] : v[k]) + r;
        }
    }
    {   const bool hi = (lane & 2) != 0;
        float s = hi ? v[0] : v[1];
        float r = __shfl_xor(s, 2);
        v[0] = (hi ? v[1] : v[0]) + r;
    }
    v[0] += __shfl_xor(v[0], 1);
    return v[0];
}

// ---------------------------------------------------------------------------
// K2a: loss partials, split 8-way over d.  Grid (8, 64), 256 threads.
// Each block computes the 152 reduction partials (16 conf-sq + 136 pair inner
// products) over its 250-d chunk and stores them to res2[b][cx][152].
// ---------------------------------------------------------------------------
extern "C" __global__ __launch_bounds__(256)
void k2a_loss(const float* __restrict__ x, const float* __restrict__ nl,
              const float* __restrict__ tgt, const float* __restrict__ W,
              const float* __restrict__ bias, float* __restrict__ res2) {
    const int cx = blockIdx.x;     // 0..7
    const int b  = blockIdx.y;     // 0..63
    const int t  = threadIdx.x;
    __shared__ float xsl[NDIN];
    __shared__ float nsl[NM * NE];
    __shared__ float tgl[252];
    __shared__ float pt[NM][252];

    {   // g-sums (linearity collapse)
        const float* xb = x + (size_t)b * NG * NDIN;
        float s = 0.f;
        for (int g = 0; g < NG; ++g) s += xb[g * NDIN + t];
        xsl[t] = s;
        const float* nb = nl + (size_t)b * NG * (NM * NE);
        float s2 = 0.f;
        for (int g = 0; g < NG; ++g) s2 += nb[g * (NM * NE) + t];
        nsl[t] = s2;
    }

    int tm = 0, tn = 0;
    if (t >= 16 && t < 152) {
        int p = t - 16;
        for (int m = 0; m < NM; ++m) {
            int c = NM - m;
            if (p < c) { tm = m; tn = m + p; break; }
            p -= c;
        }
    }
    __syncthreads();

    const int d = cx * 250 + t;
    if (t < 250) {
        tgl[t] = tgt[b * ND + d];
        float xw = 0.f;
        #pragma unroll 8
        for (int k = 0; k < NDIN; ++k) xw += xsl[k] * W[(size_t)k * ND + d];
        float we[NE];
        #pragma unroll
        for (int e = 0; e < NE; ++e) we[e] = W[(size_t)(NDIN + e) * ND + d];
        const float base0 = xw + (float)NG * bias[d];
        #pragma unroll
        for (int m = 0; m < NM; ++m) {
            float pm = base0;
            #pragma unroll
            for (int e = 0; e < NE; ++e) pm += nsl[m * NE + e] * we[e];
            pt[m][t] = pm;
        }
    }
    if (t < 32) {                      // zero-pad cols 250,251
        pt[t >> 1][250 + (t & 1)] = 0.f;
        if (t < 2) tgl[250 + t] = 0.f;
    }
    __syncthreads();

    float acc = 0.f;
    if (t < 16) {
        const float4* pa  = (const float4*)&pt[t][0];
        const float4* tga = (const float4*)&tgl[0];
        for (int i = 0; i < 63; ++i) {
            float4 pv = pa[i], tv = tga[i];
            float e0 = pv.x - tv.x, e1 = pv.y - tv.y, e2 = pv.z - tv.z, e3 = pv.w - tv.w;
            acc += e0 * e0 + e1 * e1 + e2 * e2 + e3 * e3;
        }
    } else if (t < 152) {
        const float4* pa = (const float4*)&pt[tm][0];
        const float4* pb = (const float4*)&pt[tn][0];
        for (int i = 0; i < 63; ++i) {
            float4 u = pa[i], v = pb[i];
            acc += u.x * v.x + u.y * v.y + u.z * v.z + u.w * v.w;
        }
    }
    if (t < 152) res2[((size_t)b * 8 + cx) * 152 + t] = acc;
}

// K2b: combine the 8 d-chunk partials per b and accumulate the loss.
extern "C" __global__ __launch_bounds__(64)
void k2b_combine(const float* __restrict__ res2, float* __restrict__ out) {
    const int b = blockIdx.x, t = threadIdx.x;
    __shared__ float res[152];
    for (int tau = t; tau < 152; tau += 64) {
        float s = 0.f;
        #pragma unroll
        for (int c = 0; c < 8; ++c) s += res2[((size_t)b * 8 + c) * 152 + tau];
        res[tau] = s;
    }
    __syncthreads();
    if (t == 0) {
        float conf = 0.f;
        for (int m = 0; m < NM; ++m) conf += sqrtf(res[m]);
        conf *= (1.f / NM);
        float pd = 0.f;
        for (int m = 0; m < NM; ++m) {
            const int offm = 16 + m * NM - m * (m - 1) / 2;
            const float sqm = res[offm];
            for (int n = m + 1; n < NM; ++n) {
                const int offn = 16 + n * NM - n * (n - 1) / 2;
                const float sqn = res[offn];
                const float inn = res[offm + (n - m)];
                pd += sqrtf(fmaxf(sqm + sqn - 2.f * inn, 1e-6f));
            }
        }
        pd = 2.f * pd / (float)(NM * (NM - 1));
        atomicAdd(out, (conf - 0.5f * pd) * (1.f / NB));
    }
}

// ---------------------------------------------------------------------------
// K2 fallback (round-2 single-block-per-b version, used only if ws too small)
// ---------------------------------------------------------------------------
extern "C" __global__ __launch_bounds__(256)
void k2_fallback(const float* __restrict__ x, const float* __restrict__ nl,
                 const float* __restrict__ tgt, const float* __restrict__ W,
                 const float* __restrict__ bias, float* __restrict__ out) {
    const int b = blockIdx.x, t = threadIdx.x;
    __shared__ float xsl[NDIN];
    __shared__ float nsl[NM * NE];
    __shared__ float tg[256];
    __shared__ float pt[NM][260];
    __shared__ float res[152];

    {
        const float* xb = x + (size_t)b * NG * NDIN;
        float s = 0.f;
        for (int g = 0; g < NG; ++g) s += xb[g * NDIN + t];
        xsl[t] = s;
        const float* nb = nl + (size_t)b * NG * (NM * NE);
        float s2 = 0.f;
        for (int g = 0; g < NG; ++g) s2 += nb[g * (NM * NE) + t];
        nsl[t] = s2;
    }
    int tm = 0, tn = 0;
    if (t >= 16 && t < 152) {
        int p = t - 16;
        for (int m = 0; m < NM; ++m) {
            int c = NM - m;
            if (p < c) { tm = m; tn = m + p; break; }
            p -= c;
        }
    }
    float acc = 0.f;
    for (int c0 = 0; c0 < ND; c0 += 256) {
        const int clen = min(256, ND - c0);
        __syncthreads();
        if (t < clen) {
            const int d = c0 + t;
            tg[t] = tgt[b * ND + d];
            float xw = 0.f;
            #pragma unroll 8
            for (int k = 0; k < NDIN; ++k) xw += xsl[k] * W[k * ND + d];
            float we[NE];
            #pragma unroll
            for (int e = 0; e < NE; ++e) we[e] = W[(NDIN + e) * ND + d];
            const float base0 = xw + (float)NG * bias[d];
            #pragma unroll
            for (int m = 0; m < NM; ++m) {
                float pm = base0;
                #pragma unroll
                for (int e = 0; e < NE; ++e) pm += nsl[m * NE + e] * we[e];
                pt[m][t] = pm;
            }
        }
        __syncthreads();
        if (t < 16) {
            const float4* pa  = (const float4*)&pt[t][0];
            const float4* tga = (const float4*)&tg[0];
            float a = 0.f;
            for (int i = 0; i < clen / 4; ++i) {
                float4 pv = pa[i], tv = tga[i];
                float e0 = pv.x - tv.x, e1 = pv.y - tv.y, e2 = pv.z - tv.z, e3 = pv.w - tv.w;
                a += e0 * e0 + e1 * e1 + e2 * e2 + e3 * e3;
            }
            acc += a;
        } else if (t < 152) {
            const float4* pa = (const float4*)&pt[tm][0];
            const float4* pb = (const float4*)&pt[tn][0];
            float a = 0.f;
            for (int i = 0; i < clen / 4; ++i) {
                float4 u = pa[i], v = pb[i];
                a += u.x * v.x + u.y * v.y + u.z * v.z + u.w * v.w;
            }
            acc += a;
        }
    }
    __syncthreads();
    if (t < 152) res[t] = acc;
    __syncthreads();
    if (t == 0) {
        float conf = 0.f;
        for (int m = 0; m < NM; ++m) conf += sqrtf(res[m]);
        conf *= (1.f / NM);
        float pd = 0.f;
        for (int m = 0; m < NM; ++m) {
            const int offm = 16 + m * NM - m * (m - 1) / 2;
            const float sqm = res[offm];
            for (int n = m + 1; n < NM; ++n) {
                const int offn = 16 + n * NM - n * (n - 1) / 2;
                const float sqn = res[offn];
                const float inn = res[offm + (n - m)];
                pd += sqrtf(fmaxf(sqm + sqn - 2.f * inn, 1e-6f));
            }
        }
        pd = 2.f * pd / (float)(NM * (NM - 1));
        atomicAdd(out, (conf - 0.5f * pd) * (1.f / NB));
    }
}

// ---------------------------------------------------------------------------
// K3: x_pred = softplus(concat(x, noise_sample) @ W + bias) -> ws.
// Split 4-way over d: grid (4, 256), 256 threads; thread owns 2 d for 8 rows.
// ---------------------------------------------------------------------------
extern "C" __global__ __launch_bounds__(256)
void k3_xpred(const float* __restrict__ x, const float* __restrict__ nsamp,
              const float* __restrict__ W, const float* __restrict__ bias,
              float* __restrict__ xp) {
    const int dx = blockIdx.x;     // 0..3
    const int rb = blockIdx.y;     // 0..255
    const int t  = threadIdx.x;
    __shared__ float xr[8][NK];
    #pragma unroll
    for (int r = 0; r < 8; ++r) {
        const int row = rb * 8 + r;
        xr[r][t] = x[(size_t)row * NDIN + t];
        if (t < NE) xr[r][NDIN + t] = nsamp[row * NE + t];
    }
    __syncthreads();
    if (t >= 250) return;
    const int d = dx * NDC + 2 * t;
    float acc[8][2];
    #pragma unroll
    for (int r = 0; r < 8; ++r) { acc[r][0] = 0.f; acc[r][1] = 0.f; }
    for (int k = 0; k < NK; k += 4) {
        float2 w[4];
        #pragma unroll
        for (int kk = 0; kk < 4; ++kk) w[kk] = *(const float2*)&W[(size_t)(k + kk) * ND + d];
        #pragma unroll
        for (int r = 0; r < 8; ++r) {
            const float4 xv = *(const float4*)&xr[r][k];
            acc[r][0] += xv.x * w[0].x + xv.y * w[1].x + xv.z * w[2].x + xv.w * w[3].x;
            acc[r][1] += xv.x * w[0].y + xv.y * w[1].y + xv.z * w[2].y + xv.w * w[3].y;
        }
    }
    const float2 bv = *(const float2*)&bias[d];
    #pragma unroll
    for (int r = 0; r < 8; ++r) {
        float2 o;
        o.x = softplusf(acc[r][0] + bv.x);
        o.y = softplusf(acc[r][1] + bv.y);
        *(float2*)&xp[(size_t)(rb * 8 + r) * ND + d] = o;
    }
}

// ---------------------------------------------------------------------------
// K4: IPF + final scale + integerization, 4-way d-split.  Grid (4, 64),
// 256 threads; thread owns 2 full columns (all 32 g) in registers.
// Per iteration: col phase thread-local; row phase = packed butterfly (32
// shuffles) + 4x32 LDS stage + cross-block exchange through L2 (double-
// buffered slots + monotonic arrival counter per b, spin-wait).
// Co-residency: 256 blocks == 256 CUs, 4 waves & <2 KB LDS each => all fit.
// ---------------------------------------------------------------------------
extern "C" __global__ __launch_bounds__(256)
void k4_split(const float* __restrict__ xp, const int* __restrict__ tsum,
              float* __restrict__ out, float* __restrict__ rowpart,
              int* __restrict__ cnt) {
    const int blk = blockIdx.x;    // 0..3
    const int b   = blockIdx.y;    // 0..63
    const int t   = threadIdx.x;
    const int lane = t & 63, w = t >> 6;
    const int d0 = blk * NDC + 2 * t;
    const bool act = (t < 250);

    __shared__ __align__(16) float Bl[NG];
    __shared__ float Rl[NG];
    __shared__ float wred[4][NG];

    float y0r[2][NG];
    #pragma unroll
    for (int g = 0; g < NG; ++g) {
        float2 v = make_float2(0.f, 0.f);
        if (act) v = *(const float2*)(xp + (size_t)(b * NG + g) * ND + d0);
        y0r[0][g] = fmaxf(v.x, 0.f);
        y0r[1][g] = fmaxf(v.y, 0.f);
    }
    float Cc[2] = {0.f, 0.f};
    if (act) {
        const int2 ci = *(const int2*)(tsum + (size_t)b * ND + d0);
        Cc[0] = (float)ci.x; Cc[1] = (float)ci.y;
    }
    float Ac[2] = {1.f, 1.f};
    if (t < NG) Bl[t] = 1.f;

    float* rp_b = rowpart + (size_t)b * (2 * 4 * NG);

    // ---- prologue: global row anchors R[g] (round q=0, buf 0) ----
    {
        float v[NG];
        #pragma unroll
        for (int g = 0; g < NG; ++g) v[g] = y0r[0][g] + y0r[1][g];
        const float tot = wave_sum32(v, lane);
        if ((lane & 1) == 0) wred[w][lane >> 1] = tot;
        __syncthreads();
        if (t < NG) {
            const float ps = wred[0][t] + wred[1][t] + wred[2][t] + wred[3][t];
            __hip_atomic_store(&rp_b[blk * NG + t], ps,
                               __ATOMIC_RELAXED, __HIP_MEMORY_SCOPE_AGENT);
        }
        __threadfence();
        if (t == 0) atomicAdd(&cnt[b], 1);
        if (t < NG) {
            while (__hip_atomic_load(&cnt[b], __ATOMIC_RELAXED,
                                     __HIP_MEMORY_SCOPE_AGENT) < 4)
                __builtin_amdgcn_s_sleep(1);
            float s = 0.f;
            #pragma unroll
            for (int k = 0; k < 4; ++k)
                s += __hip_atomic_load(&rp_b[k * NG + t],
                                       __ATOMIC_RELAXED, __HIP_MEMORY_SCOPE_AGENT);
            Rl[t] = s;
        }
        __syncthreads();
    }

    // ---- 60 IPF iterations (rounds q = 1..60, buf = q&1) ----
    for (int q = 1; q <= 60; ++q) {
        // col phase (thread-local)
        float Bg[NG];
        #pragma unroll
        for (int g = 0; g < NG; g += 4) {
            const float4 bv = *(const float4*)&Bl[g];
            Bg[g] = bv.x; Bg[g + 1] = bv.y; Bg[g + 2] = bv.z; Bg[g + 3] = bv.w;
        }
        float s0 = 0.f, s1 = 0.f;
        #pragma unroll
        for (int g = 0; g < NG; ++g) {
            s0 += y0r[0][g] * Bg[g];
            s1 += y0r[1][g] * Bg[g];
        }
        Ac[0] *= clampf(Cc[0] / fmaxf(Ac[0] * s0, 1e-12f), 0.75f, 1.25f);
        Ac[1] *= clampf(Cc[1] / fmaxf(Ac[1] * s1, 1e-12f), 0.75f, 1.25f);
        // row phase
        float v[NG];
        #pragma unroll
        for (int g = 0; g < NG; ++g)
            v[g] = y0r[0][g] * Ac[0] + y0r[1][g] * Ac[1];
        const float tot = wave_sum32(v, lane);
        if ((lane & 1) == 0) wred[w][lane >> 1] = tot;
        __syncthreads();
        const int buf = q & 1;
        if (t < NG) {
            const float ps = wred[0][t] + wred[1][t] + wred[2][t] + wred[3][t];
            __hip_atomic_store(&rp_b[(buf * 4 + blk) * NG + t], ps,
                               __ATOMIC_RELAXED, __HIP_MEMORY_SCOPE_AGENT);
        }
        __threadfence();
        if (t == 0) atomicAdd(&cnt[b], 1);
        if (t < NG) {
            const int target = 4 * (q + 1);
            while (__hip_atomic_load(&cnt[b], __ATOMIC_RELAXED,
                                     __HIP_MEMORY_SCOPE_AGENT) < target)
                __builtin_amdgcn_s_sleep(1);
            float s = 0.f;
            #pragma unroll
            for (int k = 0; k < 4; ++k)
                s += __hip_atomic_load(&rp_b[(buf * 4 + k) * NG + t],
                                       __ATOMIC_RELAXED, __HIP_MEMORY_SCOPE_AGENT);
            const float Bgc = Bl[t];
            Bl[t] = Bgc * clampf(Rl[t] / fmaxf(Bgc * s, 1e-12f), 0.75f, 1.25f);
        }
        __syncthreads();
    }

    // ---- epilogue: final scale + exact integerization (thread-local) ----
    if (!act) return;
    float Bf[NG];
    #pragma unroll
    for (int g = 0; g < NG; g += 4) {
        const float4 bv = *(const float4*)&Bl[g];
        Bf[g] = bv.x; Bf[g + 1] = bv.y; Bf[g + 2] = bv.z; Bf[g + 3] = bv.w;
    }
    #pragma unroll
    for (int j = 0; j < 2; ++j) {
        float fr[NG];
        int   yv[NG];
        float s = 0.f;
        #pragma unroll
        for (int g = 0; g < NG; ++g) {
            const float z = y0r[j][g] * Ac[j] * Bf[g];
            fr[g] = z;
            s += z;
        }
        const float F = Cc[j] / fmaxf(s, 1e-12f);
        int isum = 0;
        #pragma unroll
        for (int g = 0; g < NG; ++g) {
            const float y = fr[g] * F;
            const float fl = floorf(y);
            yv[g] = (int)fl;
            fr[g] = y - fl;
            isum += yv[g];
        }
        const int Ci = (int)Cc[j];
        const int need = Ci - isum;
        const int pos = max(need, 0);
        const int q = pos >> 5;
        const int r = pos & 31;
        #pragma unroll
        for (int g = 0; g < NG; ++g) yv[g] += q;
        #pragma unroll
        for (int g = 0; g < NG; ++g) {       // stable descending rank on frac
            int rank = 0;
            #pragma unroll
            for (int h = 0; h < NG; ++h) {
                if (h == g) continue;
                rank += (h < g) ? (fr[h] >= fr[g] ? 1 : 0) : (fr[h] > fr[g] ? 1 : 0);
            }
            if (rank < r) yv[g] += 1;
        }
        int neg = max(-need, 0);             // provably inert; kept for fidelity
        neg = min(neg, isum + pos);
        if (neg > 0) {
            const int q2 = neg >> 5;
            int removed = 0;
            unsigned elig = 0u;
            #pragma unroll
            for (int g = 0; g < NG; ++g) {
                const int yb = yv[g];
                const int yn = max(yb - q2, 0);
                removed += yb - yn;
                yv[g] = yn;
                if (yn > 0) elig |= (1u << g);
            }
            int r2 = neg - removed;
            for (; r2 > 0; --r2) {
                float best = __builtin_inff();
                int bi = -1;
                #pragma unroll
                for (int g = 0; g < NG; ++g) {
                    const float fm = ((elig >> g) & 1u) ? fr[g] : __builtin_inff();
                    if (fm < best) { best = fm; bi = g; }
                }
                if (bi < 0) break;
                elig &= ~(1u << bi);
                yv[bi] = max(yv[bi] - 1, 0);
            }
        }
        const size_t ob = 1 + (size_t)(b * NG) * ND + (size_t)(d0 + j);
        #pragma unroll
        for (int g = 0; g < NG; ++g)
            out[ob + (size_t)g * ND] = (float)yv[g];
    }
}

// ---------------------------------------------------------------------------
// K4 fallback (round-2 single-block-per-b, no ws control region needed)
// ---------------------------------------------------------------------------
extern "C" __global__ __launch_bounds__(512)
void k4_fallback(const float* __restrict__ xp, const int* __restrict__ tsum,
                 float* __restrict__ out) {
    const int b = blockIdx.x, t = threadIdx.x;
    const int lane = t & 63;
    const int w = t >> 6;
    const int d0 = t * 4;
    const bool valid = (d0 < ND);

    __shared__ __align__(16) float Bl[NG];
    __shared__ float Rl[NG];
    __shared__ float wred[8][NG];

    float y0r[4][NG];
    #pragma unroll
    for (int g = 0; g < NG; ++g) {
        float4 v = make_float4(0.f, 0.f, 0.f, 0.f);
        if (valid) v = *(const float4*)(xp + (size_t)(b * NG + g) * ND + d0);
        y0r[0][g] = fmaxf(v.x, 0.f);
        y0r[1][g] = fmaxf(v.y, 0.f);
        y0r[2][g] = fmaxf(v.z, 0.f);
        y0r[3][g] = fmaxf(v.w, 0.f);
    }
    float Cc[4] = {0.f, 0.f, 0.f, 0.f};
    if (valid) {
        const int4 ci = *(const int4*)(tsum + (size_t)b * ND + d0);
        Cc[0] = (float)ci.x; Cc[1] = (float)ci.y; Cc[2] = (float)ci.z; Cc[3] = (float)ci.w;
    }
    float Ac[4] = {1.f, 1.f, 1.f, 1.f};
    if (t < NG) Bl[t] = 1.f;

    {
        float v[NG];
        #pragma unroll
        for (int g = 0; g < NG; ++g)
            v[g] = y0r[0][g] + y0r[1][g] + y0r[2][g] + y0r[3][g];
        const float tot = wave_sum32(v, lane);
        if ((lane & 1) == 0) wred[w][lane >> 1] = tot;
        __syncthreads();
        if (t < NG) {
            float s = 0.f;
            #pragma unroll
            for (int w2 = 0; w2 < 8; ++w2) s += wred[w2][t];
            Rl[t] = s;
        }
        __syncthreads();
    }

    for (int it = 0; it < 60; ++it) {
        float Bg[NG];
        #pragma unroll
        for (int g = 0; g < NG; g += 4) {
            const float4 bv = *(const float4*)&Bl[g];
            Bg[g] = bv.x; Bg[g + 1] = bv.y; Bg[g + 2] = bv.z; Bg[g + 3] = bv.w;
        }
        float sj[4] = {0.f, 0.f, 0.f, 0.f};
        #pragma unroll
        for (int g = 0; g < NG; ++g) {
            const float bg = Bg[g];
            sj[0] += y0r[0][g] * bg; sj[1] += y0r[1][g] * bg;
            sj[2] += y0r[2][g] * bg; sj[3] += y0r[3][g] * bg;
        }
        #pragma unroll
        for (int j = 0; j < 4; ++j)
            Ac[j] *= clampf(Cc[j] / fmaxf(Ac[j] * sj[j], 1e-12f), 0.75f, 1.25f);
        float v[NG];
        #pragma unroll
        for (int g = 0; g < NG; ++g)
            v[g] = y0r[0][g] * Ac[0] + y0r[1][g] * Ac[1]
                 + y0r[2][g] * Ac[2] + y0r[3][g] * Ac[3];
        const float tot = wave_sum32(v, lane);
        if ((lane & 1) == 0) wred[w][lane >> 1] = tot;
        __syncthreads();
        if (t < NG) {
            float ssum = 0.f;
            #pragma unroll
            for (int w2 = 0; w2 < 8; ++w2) ssum += wred[w2][t];
            const float Bgc = Bl[t];
            Bl[t] = Bgc * clampf(Rl[t] / fmaxf(Bgc * ssum, 1e-12f), 0.75f, 1.25f);
        }
        __syncthreads();
    }

    if (!valid) return;
    #pragma unroll
    for (int j = 0; j < 4; ++j) {
        float fr[NG];
        int   yv[NG];
        float s = 0.f;
        #pragma unroll
        for (int g = 0; g < NG; ++g) {
            const float z = y0r[j][g] * Ac[j] * Bl[g];
            fr[g] = z;
            s += z;
        }
        const float F = Cc[j] / fmaxf(s, 1e-12f);
        int isum = 0;
        #pragma unroll
        for (int g = 0; g < NG; ++g) {
            const float y = fr[g] * F;
            const float fl = floorf(y);
            yv[g] = (int)fl;
            fr[g] = y - fl;
            isum += yv[g];
        }
        const int Ci = (int)Cc[j];
        const int need = Ci - isum;
        const int pos = max(need, 0);
        const int q = pos >> 5;
        const int r = pos & 31;
        #pragma unroll
        for (int g = 0; g < NG; ++g) yv[g] += q;
        #pragma unroll
        for (int g = 0; g < NG; ++g) {
            int rank = 0;
            #pragma unroll
            for (int h = 0; h < NG; ++h) {
                if (h == g) continue;
                rank += (h < g) ? (fr[h] >= fr[g] ? 1 : 0) : (fr[h] > fr[g] ? 1 : 0);
            }
            if (rank < r) yv[g] += 1;
        }
        int neg = max(-need, 0);
        neg = min(neg, isum + pos);
        if (neg > 0) {
            const int q2 = neg >> 5;
            int removed = 0;
            unsigned elig = 0u;
            #pragma unroll
            for (int g = 0; g < NG; ++g) {
                const int yb = yv[g];
                const int yn = max(yb - q2, 0);
                removed += yb - yn;
                yv[g] = yn;
                if (yn > 0) elig |= (1u << g);
            }
            int r2 = neg - removed;
            for (; r2 > 0; --r2) {
                float best = __builtin_inff();
                int bi = -1;
                #pragma unroll
                for (int g = 0; g < NG; ++g) {
                    const float fm = ((elig >> g) & 1u) ? fr[g] : __builtin_inff();
                    if (fm < best) { best = fm; bi = g; }
                }
                if (bi < 0) break;
                elig &= ~(1u << bi);
                yv[bi] = max(yv[bi] - 1, 0);
            }
        }
        const size_t ob = 1 + (size_t)(b * NG) * ND + (size_t)(d0 + j);
        #pragma unroll
        for (int g = 0; g < NG; ++g)
            out[ob + (size_t)g * ND] = (float)yv[g];
    }
}

// ---------------------------------------------------------------------------
extern "C" void kernel_launch(void* const* d_in, const int* in_sizes, int n_in,
                              void* d_out, int out_size, void* d_ws, size_t ws_size,
                              hipStream_t stream) {
    const float* x     = (const float*)d_in[0];
    const float* tgt   = (const float*)d_in[1];
    const int*   tsum  = (const int*)d_in[2];
    const float* W     = (const float*)d_in[3];
    const float* bias  = (const float*)d_in[4];
    const float* nl    = (const float*)d_in[5];
    const float* nsamp = (const float*)d_in[6];
    float* out = (float*)d_out;
    float* xp  = (float*)d_ws;                         // 2048*2000 floats

    (void)in_sizes; (void)n_in; (void)out_size;

    const size_t XPB  = (size_t)2048 * 2000 * 4;       // 16,384,000
    const size_t RPB  = (size_t)64 * 2 * 4 * NG * 4;   // 65,536
    const size_t CNTB = 256;
    const size_t RESB = (size_t)64 * 8 * 152 * 4;      // 311,296
    const size_t need = XPB + RPB + CNTB + RESB;

    hipMemsetAsync(d_out, 0, sizeof(float), stream);   // loss accumulator
    hipLaunchKernelGGL(k3_xpred, dim3(4, 256), dim3(256), 0, stream,
                       x, nsamp, W, bias, xp);

    if (ws_size >= need) {
        float* rowpart = (float*)((char*)d_ws + XPB);
        int*   cnt     = (int*)((char*)d_ws + XPB + RPB);
        float* res2    = (float*)((char*)d_ws + XPB + RPB + CNTB);
        hipMemsetAsync(cnt, 0, CNTB, stream);          // spin counters -> 0
        hipLaunchKernelGGL(k2a_loss, dim3(8, NB), dim3(256), 0, stream,
                           x, nl, tgt, W, bias, res2);
        hipLaunchKernelGGL(k2b_combine, dim3(NB), dim3(64), 0, stream, res2, out);
        hipLaunchKernelGGL(k4_split, dim3(4, NB), dim3(256), 0, stream,
                           xp, tsum, out, rowpart, cnt);
    } else {
        hipLaunchKernelGGL(k2_fallback, dim3(NB), dim3(256), 0, stream,
                           x, nl, tgt, W, bias, out);
        hipLaunchKernelGGL(k4_fallback, dim3(NB), dim3(512), 0, stream,
                           xp, tsum, out);
    }
}

// Round 5
// 318.697 us; speedup vs baseline: 4.5835x; 4.5835x over previous
//
#include <hip/hip_runtime.h>
#include <math.h>

// Problem constants (match reference)
#define NB   64     // num_groups (B)
#define NG   32     // group_size (G)
#define ND   2000   // output dim D
#define NM   16     // m_samples
#define NE   16     // noise dim
#define NDIN 256
#define NK   272    // DIN + E

__device__ __forceinline__ float clampf(float v, float lo, float hi) {
    return fminf(fmaxf(v, lo), hi);
}

__device__ __forceinline__ float softplusf(float v) {
    return (v > 20.f) ? v : log1pf(expf(v));
}

// Fully-packed butterfly: reduce v[0..31] (per-g partials) across 64 lanes in
// 32 shuffles.  On exit returns the wave total for g = (lane>>1)&31
// (duplicated on lane pairs {2g, 2g+1}).  HW-verified in round 3.
__device__ __forceinline__ float wave_sum32(float v[NG], int lane) {
    {   const bool hi = (lane & 32) != 0;
        #pragma unroll
        for (int k = 0; k < 16; ++k) {
            float s = hi ? v[k] : v[k + 16];
            float r = __shfl_xor(s, 32);
            v[k] = (hi ? v[k + 16] : v[k]) + r;
        }
    }
    {   const bool hi = (lane & 16) != 0;
        #pragma unroll
        for (int k = 0; k < 8; ++k) {
            float s = hi ? v[k] : v[k + 8];
            float r = __shfl_xor(s, 16);
            v[k] = (hi ? v[k + 8] : v[k]) + r;
        }
    }
    {   const bool hi = (lane & 8) != 0;
        #pragma unroll
        for (int k = 0; k < 4; ++k) {
            float s = hi ? v[k] : v[k + 4];
            float r = __shfl_xor(s, 8);
            v[k] = (hi ? v[k + 4] : v[k]) + r;
        }
    }
    {   const bool hi = (lane & 4) != 0;
        #pragma unroll
        for (int k = 0; k < 2; ++k) {
            float s = hi ? v[k] : v[k + 2];
            float r = __shfl_xor(s, 4);
            v[k] = (hi ? v[k + 2] : v[k]) + r;
        }
    }
    {   const bool hi = (lane & 2) != 0;
        float s = hi ? v[0] : v[1];
        float r = __shfl_xor(s, 2);
        v[0] = (hi ? v[1] : v[0]) + r;
    }
    v[0] += __shfl_xor(v[0], 1);
    return v[0];
}

// ---------------------------------------------------------------------------
// Mega kernel: grid 576 x 512 threads.
//   blocks 0..63   : IPF + final scale + integerization for b = blockIdx.x
//   blocks 64..575 : loss partials (8 d-chunks x 64 b = 512 blocks)
// The two paths are independent; fusing them fills the CUs that the 64
// latency-bound IPF blocks leave idle.  (Round-3 lesson: never sync across
// workgroups per iteration — all cross-thread traffic here is block-local.)
// ---------------------------------------------------------------------------

// ---- IPF path: one block per b, 512 threads, thread owns d = 4t..4t+3 ----
// Per iteration: col phase thread-local; row phase = packed butterfly +
// ONE barrier (double-buffered wred) + redundant distributed B update.
__device__ __forceinline__ void ipf_path(
        const float* __restrict__ xp, const int* __restrict__ tsum,
        float* __restrict__ out, float* smem, int b, int t) {
    const int lane = t & 63, w = t >> 6;
    const int d0 = t * 4;
    const bool valid = (d0 < ND);          // t < 500
    const int g_own = (lane >> 1) & 31;

    float* wred = smem;                    // [2][8][32] floats, double-buffered

    // load y0 = max(x_pred, 0)
    float y0r[4][NG];
    #pragma unroll
    for (int g = 0; g < NG; ++g) {
        float4 v = make_float4(0.f, 0.f, 0.f, 0.f);
        if (valid) v = *(const float4*)(xp + (size_t)(b * NG + g) * ND + d0);
        y0r[0][g] = fmaxf(v.x, 0.f);
        y0r[1][g] = fmaxf(v.y, 0.f);
        y0r[2][g] = fmaxf(v.z, 0.f);
        y0r[3][g] = fmaxf(v.w, 0.f);
    }
    float Cc[4] = {0.f, 0.f, 0.f, 0.f};
    if (valid) {
        const int4 ci = *(const int4*)(tsum + (size_t)b * ND + d0);
        Cc[0] = (float)ci.x; Cc[1] = (float)ci.y; Cc[2] = (float)ci.z; Cc[3] = (float)ci.w;
    }
    float Ac[4] = {1.f, 1.f, 1.f, 1.f};
    float Bown = 1.f;                      // this lane-pair's B[g_own]
    float Rown;                            // this lane-pair's R[g_own]

    // prologue: row anchors R (uses wred buf 0)
    {
        float v[NG];
        #pragma unroll
        for (int g = 0; g < NG; ++g)
            v[g] = y0r[0][g] + y0r[1][g] + y0r[2][g] + y0r[3][g];
        const float tot = wave_sum32(v, lane);
        if ((lane & 1) == 0) wred[w * NG + g_own] = tot;
        __syncthreads();
        float s = 0.f;
        #pragma unroll
        for (int w2 = 0; w2 < 8; ++w2) s += wred[w2 * NG + g_own];
        Rown = s;
    }

    // 60 IPF iterations, ONE barrier each
    for (int q = 1; q <= 60; ++q) {
        // materialize B[0..31] from distributed Bown (uniform-lane shuffles)
        float Bg[NG];
        #pragma unroll
        for (int g = 0; g < NG; ++g) Bg[g] = __shfl(Bown, 2 * g);
        // column phase (thread-local)
        float s0 = 0.f, s1 = 0.f, s2 = 0.f, s3 = 0.f;
        #pragma unroll
        for (int g = 0; g < NG; ++g) {
            const float bg = Bg[g];
            s0 += y0r[0][g] * bg; s1 += y0r[1][g] * bg;
            s2 += y0r[2][g] * bg; s3 += y0r[3][g] * bg;
        }
        Ac[0] *= clampf(Cc[0] / fmaxf(Ac[0] * s0, 1e-12f), 0.75f, 1.25f);
        Ac[1] *= clampf(Cc[1] / fmaxf(Ac[1] * s1, 1e-12f), 0.75f, 1.25f);
        Ac[2] *= clampf(Cc[2] / fmaxf(Ac[2] * s2, 1e-12f), 0.75f, 1.25f);
        Ac[3] *= clampf(Cc[3] / fmaxf(Ac[3] * s3, 1e-12f), 0.75f, 1.25f);
        // row phase
        float v[NG];
        #pragma unroll
        for (int g = 0; g < NG; ++g)
            v[g] = y0r[0][g] * Ac[0] + y0r[1][g] * Ac[1]
                 + y0r[2][g] * Ac[2] + y0r[3][g] * Ac[3];
        const float tot = wave_sum32(v, lane);
        const int buf = (q & 1) * (8 * NG);
        if ((lane & 1) == 0) wred[buf + w * NG + g_own] = tot;
        __syncthreads();
        float s = 0.f;
        #pragma unroll
        for (int w2 = 0; w2 < 8; ++w2) s += wred[buf + w2 * NG + g_own];
        Bown *= clampf(Rown / fmaxf(Bown * s, 1e-12f), 0.75f, 1.25f);
    }

    // epilogue: final scale + exact integerization, thread-local; results
    // byte-packed per g; 4 consecutive dword stores per g (wave-coalesced).
    if (!valid) return;
    float Bg[NG];
    #pragma unroll
    for (int g = 0; g < NG; ++g) Bg[g] = __shfl(Bown, 2 * g);

    unsigned pk[NG];
    #pragma unroll
    for (int g = 0; g < NG; ++g) pk[g] = 0u;

    #pragma unroll
    for (int j = 0; j < 4; ++j) {
        float fr[NG];
        int   yv[NG];
        float s = 0.f;
        #pragma unroll
        for (int g = 0; g < NG; ++g) {
            const float z = y0r[j][g] * Ac[j] * Bg[g];
            fr[g] = z;
            s += z;
        }
        const float F = Cc[j] / fmaxf(s, 1e-12f);
        int isum = 0;
        #pragma unroll
        for (int g = 0; g < NG; ++g) {
            const float y = fr[g] * F;
            const float fl = floorf(y);
            yv[g] = (int)fl;
            fr[g] = y - fl;
            isum += yv[g];
        }
        const int Ci = (int)Cc[j];
        const int need = Ci - isum;
        const int pos = max(need, 0);
        const int q = pos >> 5;
        const int r = pos & 31;
        #pragma unroll
        for (int g = 0; g < NG; ++g) yv[g] += q;
        #pragma unroll
        for (int g = 0; g < NG; ++g) {       // stable descending rank on frac
            int rank = 0;
            #pragma unroll
            for (int h = 0; h < NG; ++h) {
                if (h == g) continue;
                rank += (h < g) ? (fr[h] >= fr[g] ? 1 : 0) : (fr[h] > fr[g] ? 1 : 0);
            }
            if (rank < r) yv[g] += 1;
        }
        int neg = max(-need, 0);             // provably inert; kept for fidelity
        neg = min(neg, isum + pos);
        if (neg > 0) {
            const int q2 = neg >> 5;
            int removed = 0;
            unsigned elig = 0u;
            #pragma unroll
            for (int g = 0; g < NG; ++g) {
                const int yb = yv[g];
                const int yn = max(yb - q2, 0);
                removed += yb - yn;
                yv[g] = yn;
                if (yn > 0) elig |= (1u << g);
            }
            int r2 = neg - removed;
            for (; r2 > 0; --r2) {
                float best = __builtin_inff();
                int bi = -1;
                #pragma unroll
                for (int g = 0; g < NG; ++g) {
                    const float fm = ((elig >> g) & 1u) ? fr[g] : __builtin_inff();
                    if (fm < best) { best = fm; bi = g; }
                }
                if (bi < 0) break;
                elig &= ~(1u << bi);
                yv[bi] = max(yv[bi] - 1, 0);
            }
        }
        #pragma unroll
        for (int g = 0; g < NG; ++g)
            pk[g] |= ((unsigned)yv[g]) << (8 * j);   // yv <= C <= 199 < 256
    }
    #pragma unroll
    for (int g = 0; g < NG; ++g) {
        float* op = &out[1 + (size_t)(b * NG + g) * ND + d0];
        op[0] = (float)(pk[g] & 0xffu);
        op[1] = (float)((pk[g] >> 8) & 0xffu);
        op[2] = (float)((pk[g] >> 16) & 0xffu);
        op[3] = (float)((pk[g] >> 24) & 0xffu);
    }
}

// ---- loss-partials path: 512 blocks = 8 d-chunks x 64 b, 512 threads ----
__device__ __forceinline__ void loss_path(
        const float* __restrict__ x, const float* __restrict__ nl,
        const float* __restrict__ tgt, const float* __restrict__ W,
        const float* __restrict__ bias, float* __restrict__ res2,
        float* smem, int cx, int b, int t) {
    float* xsl = smem;                 // 256
    float* nsl = smem + 256;           // 256
    float* tgl = smem + 512;           // 252
    float* pt  = smem + 764;           // 16 x 252

    if (t < 256) {
        const float* xb = x + (size_t)b * NG * NDIN;
        float s = 0.f;
        for (int g = 0; g < NG; ++g) s += xb[g * NDIN + t];
        xsl[t] = s;
        const float* nb = nl + (size_t)b * NG * (NM * NE);
        float s2 = 0.f;
        for (int g = 0; g < NG; ++g) s2 += nb[g * (NM * NE) + t];
        nsl[t] = s2;
    }

    int tm = 0, tn = 0;
    if (t >= 16 && t < 152) {
        int p = t - 16;
        for (int m = 0; m < NM; ++m) {
            int c = NM - m;
            if (p < c) { tm = m; tn = m + p; break; }
            p -= c;
        }
    }
    __syncthreads();

    const int d = cx * 250 + t;
    if (t < 250) {
        tgl[t] = tgt[b * ND + d];
        float xw = 0.f;
        #pragma unroll 8
        for (int k = 0; k < NDIN; ++k) xw += xsl[k] * W[(size_t)k * ND + d];
        float we[NE];
        #pragma unroll
        for (int e = 0; e < NE; ++e) we[e] = W[(size_t)(NDIN + e) * ND + d];
        const float base0 = xw + (float)NG * bias[d];
        #pragma unroll
        for (int m = 0; m < NM; ++m) {
            float pm = base0;
            #pragma unroll
            for (int e = 0; e < NE; ++e) pm += nsl[m * NE + e] * we[e];
            pt[m * 252 + t] = pm;
        }
    }
    if (t < 32) {                      // zero-pad cols 250,251
        pt[(t >> 1) * 252 + 250 + (t & 1)] = 0.f;
        if (t < 2) tgl[250 + t] = 0.f;
    }
    __syncthreads();

    float acc = 0.f;
    if (t < 16) {
        const float4* pa  = (const float4*)&pt[t * 252];
        const float4* tga = (const float4*)&tgl[0];
        for (int i = 0; i < 63; ++i) {
            float4 pv = pa[i], tv = tga[i];
            float e0 = pv.x - tv.x, e1 = pv.y - tv.y, e2 = pv.z - tv.z, e3 = pv.w - tv.w;
            acc += e0 * e0 + e1 * e1 + e2 * e2 + e3 * e3;
        }
    } else if (t < 152) {
        const float4* pa = (const float4*)&pt[tm * 252];
        const float4* pb = (const float4*)&pt[tn * 252];
        for (int i = 0; i < 63; ++i) {
            float4 u = pa[i], v = pb[i];
            acc += u.x * v.x + u.y * v.y + u.z * v.z + u.w * v.w;
        }
    }
    if (t < 152) res2[((size_t)b * 8 + cx) * 152 + t] = acc;
}

extern "C" __global__ __launch_bounds__(512)
void mega(const float* __restrict__ x, const float* __restrict__ nl,
          const float* __restrict__ tgt, const float* __restrict__ W,
          const float* __restrict__ bias, const float* __restrict__ xp,
          const int* __restrict__ tsum, float* __restrict__ out,
          float* __restrict__ res2) {
    __shared__ float smem[4800];       // 19.2 KB, union of both paths
    const int bid = blockIdx.x;
    const int t = threadIdx.x;
    if (bid < NB) {
        ipf_path(xp, tsum, out, smem, bid, t);
    } else {
        const int q = bid - NB;        // 0..511 -> 8 chunks x 64 b
        loss_path(x, nl, tgt, W, bias, res2, smem, q & 7, q >> 3, t);
    }
}

// K2b: combine the 8 d-chunk partials per b and accumulate the loss.
extern "C" __global__ __launch_bounds__(64)
void k2b_combine(const float* __restrict__ res2, float* __restrict__ out) {
    const int b = blockIdx.x, t = threadIdx.x;
    __shared__ float res[152];
    for (int tau = t; tau < 152; tau += 64) {
        float s = 0.f;
        #pragma unroll
        for (int c = 0; c < 8; ++c) s += res2[((size_t)b * 8 + c) * 152 + tau];
        res[tau] = s;
    }
    __syncthreads();
    if (t == 0) {
        float conf = 0.f;
        for (int m = 0; m < NM; ++m) conf += sqrtf(res[m]);
        conf *= (1.f / NM);
        float pd = 0.f;
        for (int m = 0; m < NM; ++m) {
            const int offm = 16 + m * NM - m * (m - 1) / 2;
            const float sqm = res[offm];
            for (int n = m + 1; n < NM; ++n) {
                const int offn = 16 + n * NM - n * (n - 1) / 2;
                const float sqn = res[offn];
                const float inn = res[offm + (n - m)];
                pd += sqrtf(fmaxf(sqm + sqn - 2.f * inn, 1e-6f));
            }
        }
        pd = 2.f * pd / (float)(NM * (NM - 1));
        atomicAdd(out, (conf - 0.5f * pd) * (1.f / NB));
    }
}

// ---------------------------------------------------------------------------
// K3: x_pred = softplus(concat(x, noise_sample) @ W + bias) -> ws.
// Split 4-way over d: grid (4, 256), 256 threads; thread owns 2 d for 8 rows.
// ---------------------------------------------------------------------------
extern "C" __global__ __launch_bounds__(256)
void k3_xpred(const float* __restrict__ x, const float* __restrict__ nsamp,
              const float* __restrict__ W, const float* __restrict__ bias,
              float* __restrict__ xp) {
    const int dx = blockIdx.x;     // 0..3
    const int rb = blockIdx.y;     // 0..255
    const int t  = threadIdx.x;
    __shared__ float xr[8][NK];
    #pragma unroll
    for (int r = 0; r < 8; ++r) {
        const int row = rb * 8 + r;
        xr[r][t] = x[(size_t)row * NDIN + t];
        if (t < NE) xr[r][NDIN + t] = nsamp[row * NE + t];
    }
    __syncthreads();
    if (t >= 250) return;
    const int d = dx * 500 + 2 * t;
    float acc[8][2];
    #pragma unroll
    for (int r = 0; r < 8; ++r) { acc[r][0] = 0.f; acc[r][1] = 0.f; }
    for (int k = 0; k < NK; k += 4) {
        float2 w[4];
        #pragma unroll
        for (int kk = 0; kk < 4; ++kk) w[kk] = *(const float2*)&W[(size_t)(k + kk) * ND + d];
        #pragma unroll
        for (int r = 0; r < 8; ++r) {
            const float4 xv = *(const float4*)&xr[r][k];
            acc[r][0] += xv.x * w[0].x + xv.y * w[1].x + xv.z * w[2].x + xv.w * w[3].x;
            acc[r][1] += xv.x * w[0].y + xv.y * w[1].y + xv.z * w[2].y + xv.w * w[3].y;
        }
    }
    const float2 bv = *(const float2*)&bias[d];
    #pragma unroll
    for (int r = 0; r < 8; ++r) {
        float2 o;
        o.x = softplusf(acc[r][0] + bv.x);
        o.y = softplusf(acc[r][1] + bv.y);
        *(float2*)&xp[(size_t)(rb * 8 + r) * ND + d] = o;
    }
}

// ---------------------------------------------------------------------------
extern "C" void kernel_launch(void* const* d_in, const int* in_sizes, int n_in,
                              void* d_out, int out_size, void* d_ws, size_t ws_size,
                              hipStream_t stream) {
    const float* x     = (const float*)d_in[0];
    const float* tgt   = (const float*)d_in[1];
    const int*   tsum  = (const int*)d_in[2];
    const float* W     = (const float*)d_in[3];
    const float* bias  = (const float*)d_in[4];
    const float* nl    = (const float*)d_in[5];
    const float* nsamp = (const float*)d_in[6];
    float* out = (float*)d_out;
    float* xp  = (float*)d_ws;                         // 2048*2000 floats

    (void)in_sizes; (void)n_in; (void)out_size; (void)ws_size;

    const size_t XPB = (size_t)2048 * 2000 * 4;        // 16,384,000 B
    float* res2 = (float*)((char*)d_ws + XPB);         // 64*8*152 floats

    hipMemsetAsync(d_out, 0, sizeof(float), stream);   // loss accumulator

    hipLaunchKernelGGL(k3_xpred, dim3(4, 256), dim3(256), 0, stream,
                       x, nsamp, W, bias, xp);
    hipLaunchKernelGGL(mega, dim3(NB + 512), dim3(512), 0, stream,
                       x, nl, tgt, W, bias, xp, tsum, out, res2);
    hipLaunchKernelGGL(k2b_combine, dim3(NB), dim3(64), 0, stream, res2, out);
}